// Round 1
// baseline (252.980 us; speedup 1.0000x reference)
//
#include <hip/hip_runtime.h>

#define B_ 2
#define S_ 2048
#define D_ 1024
#define H_ 16
#define HW_ 64

typedef __attribute__((ext_vector_type(8))) short s16x8;
typedef __attribute__((ext_vector_type(4))) float f32x4;

__device__ __forceinline__ float bf2f(unsigned short u) {
  unsigned int x = ((unsigned int)u) << 16;
  return __builtin_bit_cast(float, x);
}
__device__ __forceinline__ unsigned short f2bf(float f) {
  unsigned int x = __builtin_bit_cast(unsigned int, f);
  x += 0x7fffu + ((x >> 16) & 1u);
  return (unsigned short)(x >> 16);
}

// ---------------- f32 -> bf16 convert (vectorized, 8 elems/thread) ----------
__global__ __launch_bounds__(256) void cvt_f32_bf16(const float* __restrict__ src,
                                                    unsigned short* __restrict__ dst,
                                                    int n8) {
  int i = blockIdx.x * 256 + threadIdx.x;
  if (i >= n8) return;
  const float4* s = (const float4*)src;
  float4 a = s[2 * i], b = s[2 * i + 1];
  s16x8 o;
  o[0] = (short)f2bf(a.x); o[1] = (short)f2bf(a.y);
  o[2] = (short)f2bf(a.z); o[3] = (short)f2bf(a.w);
  o[4] = (short)f2bf(b.x); o[5] = (short)f2bf(b.y);
  o[6] = (short)f2bf(b.z); o[7] = (short)f2bf(b.w);
  ((s16x8*)dst)[i] = o;
}

// ---------------- QKV projection GEMM: C = X(bf16) * W^T + bias -------------
// 128x128 tile, BK=64, 4 waves, wave=64x64, 16x16x32 bf16 MFMA.
// LDS rows padded to 72 ushorts (144B) -> frag reads 2-way (free).
__global__ __launch_bounds__(256) void qkv_gemm(const unsigned short* __restrict__ X,
                                                const unsigned short* __restrict__ W3,
                                                const float* __restrict__ bq,
                                                const float* __restrict__ bk,
                                                const float* __restrict__ bv,
                                                unsigned short* __restrict__ O3) {
  const int mat = blockIdx.z;
  const unsigned short* Wp = W3 + (size_t)mat * (D_ * D_);
  const float* bias = (mat == 0) ? bq : (mat == 1) ? bk : bv;
  unsigned short* Op = O3 + (size_t)mat * ((size_t)B_ * S_ * D_);

  const int bm = blockIdx.y * 128, bn = blockIdx.x * 128;
  const int tid = threadIdx.x;
  const int lane = tid & 63, w = tid >> 6;
  const int wr = (w >> 1) * 64, wc = (w & 1) * 64;
  const int l15 = lane & 15, lh = lane >> 4;

  __shared__ __align__(16) unsigned short Al[128][72];
  __shared__ __align__(16) unsigned short Wl[128][72];

  f32x4 acc[4][4];
#pragma unroll
  for (int m = 0; m < 4; ++m)
#pragma unroll
    for (int n = 0; n < 4; ++n) acc[m][n] = (f32x4){0.f, 0.f, 0.f, 0.f};

  const int sr = tid >> 3, ss = tid & 7;

  for (int k0 = 0; k0 < D_; k0 += 64) {
    __syncthreads();
#pragma unroll
    for (int i = 0; i < 4; ++i) {
      int r = i * 32 + sr;
      *(s16x8*)(&Al[r][ss * 8]) =
          *(const s16x8*)(X + (size_t)(bm + r) * D_ + k0 + ss * 8);
      *(s16x8*)(&Wl[r][ss * 8]) =
          *(const s16x8*)(Wp + (size_t)(bn + r) * D_ + k0 + ss * 8);
    }
    __syncthreads();
#pragma unroll
    for (int kb = 0; kb < 2; ++kb) {
      s16x8 af[4], wf[4];
#pragma unroll
      for (int m = 0; m < 4; ++m)
        af[m] = *(const s16x8*)(&Al[wr + m * 16 + l15][kb * 32 + lh * 8]);
#pragma unroll
      for (int n = 0; n < 4; ++n)
        wf[n] = *(const s16x8*)(&Wl[wc + n * 16 + l15][kb * 32 + lh * 8]);
#pragma unroll
      for (int m = 0; m < 4; ++m)
#pragma unroll
        for (int n = 0; n < 4; ++n)
          acc[m][n] =
              __builtin_amdgcn_mfma_f32_16x16x32_bf16(af[m], wf[n], acc[m][n], 0, 0, 0);
    }
  }

#pragma unroll
  for (int n = 0; n < 4; ++n) {
    int col = bn + wc + n * 16 + l15;
    float bval = bias[col];
#pragma unroll
    for (int m = 0; m < 4; ++m) {
      int row0 = bm + wr + m * 16 + lh * 4;
#pragma unroll
      for (int r = 0; r < 4; ++r)
        Op[(size_t)(row0 + r) * D_ + col] = f2bf(acc[m][n][r] + bval);
    }
  }
}

// ---------------- V transpose: [B*S][D] -> [B][H][64][S] --------------------
// scalar-LDS transpose with stride-65 (odd) padding -> conflict-free-ish.
__global__ __launch_bounds__(256) void vt_kernel(const unsigned short* __restrict__ Vin,
                                                 unsigned short* __restrict__ VT) {
  __shared__ unsigned short t[64][65];
  const int st = blockIdx.x, h = blockIdx.y, b = blockIdx.z;
  const int tid = threadIdx.x;
  const int r = tid >> 3, s = tid & 7;
#pragma unroll
  for (int i = 0; i < 2; ++i) {
    int key = i * 32 + r;
    s16x8 v = *(const s16x8*)(Vin + (size_t)(b * S_ + st * 64 + key) * D_ + h * HW_ + s * 8);
#pragma unroll
    for (int j = 0; j < 8; ++j) t[key][s * 8 + j] = (unsigned short)v[j];
  }
  __syncthreads();
#pragma unroll
  for (int i = 0; i < 2; ++i) {
    int d = i * 32 + r;
    s16x8 v;
#pragma unroll
    for (int j = 0; j < 8; ++j) v[j] = (short)t[s * 8 + j][d];
    *(s16x8*)(VT + ((size_t)(b * H_ + h) * HW_ + d) * S_ + st * 64 + s * 8) = v;
  }
}

// ---------------- fused flash attention ------------------------------------
// grid (H, S/64, B), 256 threads = 4 waves; wave owns 16 q-rows.
// scores layout (16x16x32 MFMA C): col = lane&15 (key), row = (lane>>4)*4+reg (q).
__global__ __launch_bounds__(256) void attn_kernel(const unsigned short* __restrict__ Q,
                                                   const unsigned short* __restrict__ K,
                                                   const unsigned short* __restrict__ VT,
                                                   const unsigned short* __restrict__ POS,
                                                   const int* __restrict__ MASK,
                                                   float* __restrict__ OUT) {
  const int h = blockIdx.x, qt = blockIdx.y, b = blockIdx.z;
  const int tid = threadIdx.x;
  const int lane = tid & 63, w = tid >> 6;
  const int l15 = lane & 15, lh = lane >> 4;

  __shared__ __align__(16) unsigned short Kl[64][72];   // [key][d]
  __shared__ __align__(16) unsigned short Vl[64][72];   // [d][key]  (from VT)
  __shared__ __align__(16) unsigned short Pl[4][16][72]; // per-wave [q][key]
  __shared__ float mbias[S_];

  for (int i = tid; i < S_; i += 256)
    mbias[i] = -10000.0f * (1.0f - (float)MASK[b * S_ + i]);

  const int q0 = qt * 64 + w * 16;
  s16x8 qf[2];
  {
    const unsigned short* qp = Q + (size_t)(b * S_ + q0 + l15) * D_ + h * HW_ + lh * 8;
    qf[0] = *(const s16x8*)qp;
    qf[1] = *(const s16x8*)(qp + 32);
  }

  f32x4 Oc[4];
#pragma unroll
  for (int n = 0; n < 4; ++n) Oc[n] = (f32x4){0.f, 0.f, 0.f, 0.f};
  float mrun[4] = {-1e30f, -1e30f, -1e30f, -1e30f};
  float lrun[4] = {0.f, 0.f, 0.f, 0.f};

  const int sr = tid >> 3, ss = tid & 7;
  const unsigned short* Kbase = K + (size_t)b * S_ * D_ + h * HW_;
  const unsigned short* Vbase = VT + ((size_t)(b * H_ + h) * HW_) * S_;
  const unsigned short* Pbase = POS + ((size_t)b * S_) * S_;

  for (int kt = 0; kt < S_ / 64; ++kt) {
    const int k0 = kt * 64;
    __syncthreads();
#pragma unroll
    for (int i = 0; i < 2; ++i) {
      int idx = i * 256 + tid;
      int r = idx >> 3, s = idx & 7;
      *(s16x8*)(&Kl[r][s * 8]) =
          *(const s16x8*)(Kbase + (size_t)(k0 + r) * D_ + s * 8);
      *(s16x8*)(&Vl[r][s * 8]) =
          *(const s16x8*)(Vbase + (size_t)r * S_ + k0 + s * 8);
    }
    __syncthreads();

    // QK^T
    f32x4 sc[4];
#pragma unroll
    for (int n = 0; n < 4; ++n) {
      s16x8 kf0 = *(const s16x8*)(&Kl[n * 16 + l15][lh * 8]);
      s16x8 kf1 = *(const s16x8*)(&Kl[n * 16 + l15][32 + lh * 8]);
      f32x4 s0 = (f32x4){0.f, 0.f, 0.f, 0.f};
      s0 = __builtin_amdgcn_mfma_f32_16x16x32_bf16(qf[0], kf0, s0, 0, 0, 0);
      s0 = __builtin_amdgcn_mfma_f32_16x16x32_bf16(qf[1], kf1, s0, 0, 0, 0);
      sc[n] = s0;
    }

    // scale + pos + mask
#pragma unroll
    for (int n = 0; n < 4; ++n) {
      int kg = k0 + n * 16 + l15;
      float mb = mbias[kg];
#pragma unroll
      for (int r = 0; r < 4; ++r) {
        int qg = q0 + lh * 4 + r;
        float p = bf2f(Pbase[(size_t)qg * S_ + kg]);
        sc[n][r] = sc[n][r] * 0.125f + p + mb;
      }
    }

    // online softmax
    float alpha[4];
#pragma unroll
    for (int r = 0; r < 4; ++r) {
      float v = fmaxf(fmaxf(sc[0][r], sc[1][r]), fmaxf(sc[2][r], sc[3][r]));
#pragma unroll
      for (int off = 1; off < 16; off <<= 1) v = fmaxf(v, __shfl_xor(v, off, 64));
      float mnew = fmaxf(mrun[r], v);
      alpha[r] = __expf(mrun[r] - mnew);
      mrun[r] = mnew;
    }
    float rs[4] = {0.f, 0.f, 0.f, 0.f};
#pragma unroll
    for (int n = 0; n < 4; ++n)
#pragma unroll
      for (int r = 0; r < 4; ++r) {
        float p = __expf(sc[n][r] - mrun[r]);
        sc[n][r] = p;
        rs[r] += p;
      }
#pragma unroll
    for (int r = 0; r < 4; ++r) {
      float s = rs[r];
#pragma unroll
      for (int off = 1; off < 16; off <<= 1) s += __shfl_xor(s, off, 64);
      lrun[r] = lrun[r] * alpha[r] + s;
    }

    // rescale O, stash P (bf16) to per-wave LDS for re-layout
#pragma unroll
    for (int n = 0; n < 4; ++n) {
#pragma unroll
      for (int r = 0; r < 4; ++r) Oc[n][r] *= alpha[r];
#pragma unroll
      for (int r = 0; r < 4; ++r)
        Pl[w][lh * 4 + r][n * 16 + l15] = f2bf(sc[n][r]);
    }

    // PV (same-wave LDS RAW: HW processes DS ops in order per wave)
#pragma unroll
    for (int kb = 0; kb < 2; ++kb) {
      s16x8 pf = *(const s16x8*)(&Pl[w][l15][kb * 32 + lh * 8]);
#pragma unroll
      for (int n = 0; n < 4; ++n) {
        s16x8 vf = *(const s16x8*)(&Vl[n * 16 + l15][kb * 32 + lh * 8]);
        Oc[n] = __builtin_amdgcn_mfma_f32_16x16x32_bf16(pf, vf, Oc[n], 0, 0, 0);
      }
    }
  }

#pragma unroll
  for (int r = 0; r < 4; ++r) {
    float inv = 1.0f / lrun[r];
    int qg = q0 + lh * 4 + r;
#pragma unroll
    for (int n = 0; n < 4; ++n)
      OUT[(size_t)(b * S_ + qg) * D_ + h * HW_ + n * 16 + l15] = Oc[n][r] * inv;
  }
}

// ---------------- launcher ---------------------------------------------------
extern "C" void kernel_launch(void* const* d_in, const int* in_sizes, int n_in,
                              void* d_out, int out_size, void* d_ws, size_t ws_size,
                              hipStream_t stream) {
  const float* x   = (const float*)d_in[0];
  const int*   msk = (const int*)d_in[1];
  const float* pos = (const float*)d_in[2];
  const float* wq  = (const float*)d_in[3];
  const float* bq  = (const float*)d_in[4];
  const float* wk  = (const float*)d_in[5];
  const float* bk  = (const float*)d_in[6];
  const float* wv  = (const float*)d_in[7];
  const float* bv  = (const float*)d_in[8];
  float* out = (float*)d_out;

  char* ws = (char*)d_ws;
  // layout: xb(8MB) | wb(6MB) | qkv(24MB) | posb(16MB) | vt(8MB)
  unsigned short* xb   = (unsigned short*)(ws);
  unsigned short* wb   = (unsigned short*)(ws + 8388608);
  unsigned short* qkv  = (unsigned short*)(ws + 14680064);
  unsigned short* posb = (unsigned short*)(ws + 39845888);
  unsigned short* vt   = (unsigned short*)(ws + 56623104);

  cvt_f32_bf16<<<2048, 256, 0, stream>>>(x, xb, (B_ * S_ * D_) / 8);
  cvt_f32_bf16<<<512, 256, 0, stream>>>(wq, wb, (D_ * D_) / 8);
  cvt_f32_bf16<<<512, 256, 0, stream>>>(wk, wb + D_ * D_, (D_ * D_) / 8);
  cvt_f32_bf16<<<512, 256, 0, stream>>>(wv, wb + 2 * D_ * D_, (D_ * D_) / 8);
  cvt_f32_bf16<<<4096, 256, 0, stream>>>(pos, posb, (B_ * S_ * S_) / 8);

  qkv_gemm<<<dim3(D_ / 128, (B_ * S_) / 128, 3), 256, 0, stream>>>(
      xb, wb, bq, bk, bv, qkv);

  vt_kernel<<<dim3(S_ / 64, H_, B_), 256, 0, stream>>>(
      qkv + 2 * (size_t)B_ * S_ * D_, vt);

  attn_kernel<<<dim3(H_, S_ / 64, B_), 256, 0, stream>>>(
      qkv, qkv + (size_t)B_ * S_ * D_, vt, posb, msk, out);
}

// Round 2
// 182.200 us; speedup vs baseline: 1.3885x; 1.3885x over previous
//
#include <hip/hip_runtime.h>

#define B_ 2
#define S_ 2048
#define D_ 1024
#define H_ 16
#define HW_ 64

typedef __attribute__((ext_vector_type(8))) short s16x8;
typedef __attribute__((ext_vector_type(4))) float f32x4;
typedef __attribute__((ext_vector_type(4))) unsigned short u16x4;
typedef __attribute__((ext_vector_type(2))) unsigned int u32x2;

__device__ __forceinline__ float bf2f(unsigned short u) {
  unsigned int x = ((unsigned int)u) << 16;
  return __builtin_bit_cast(float, x);
}
__device__ __forceinline__ unsigned short f2bf(float f) {
  unsigned int x = __builtin_bit_cast(unsigned int, f);
  x += 0x7fffu + ((x >> 16) & 1u);
  return (unsigned short)(x >> 16);
}

// ---------------- f32 -> bf16 convert (vectorized, 8 elems/thread) ----------
__global__ __launch_bounds__(256) void cvt_f32_bf16(const float* __restrict__ src,
                                                    unsigned short* __restrict__ dst,
                                                    int n8) {
  int i = blockIdx.x * 256 + threadIdx.x;
  if (i >= n8) return;
  const float4* s = (const float4*)src;
  float4 a = s[2 * i], b = s[2 * i + 1];
  s16x8 o;
  o[0] = (short)f2bf(a.x); o[1] = (short)f2bf(a.y);
  o[2] = (short)f2bf(a.z); o[3] = (short)f2bf(a.w);
  o[4] = (short)f2bf(b.x); o[5] = (short)f2bf(b.y);
  o[6] = (short)f2bf(b.z); o[7] = (short)f2bf(b.w);
  ((s16x8*)dst)[i] = o;
}

// ---------------- pos convert: bf16( pos*log2e + (mask?0:-14427) ) ----------
__global__ __launch_bounds__(256) void cvt_pos(const float* __restrict__ pos,
                                               const int* __restrict__ mask,
                                               unsigned short* __restrict__ dst) {
  int i = blockIdx.x * 256 + threadIdx.x;  // 8 elems per thread
  int e = i * 8;
  int b = e / (S_ * S_);
  int k = e & (S_ - 1);
  const float4* s = (const float4*)pos;
  float4 a = s[2 * i], c = s[2 * i + 1];
  const int* mrow = mask + b * S_ + k;
  const float L2E = 1.4426950408889634f;
  float f[8] = {a.x, a.y, a.z, a.w, c.x, c.y, c.z, c.w};
  s16x8 o;
#pragma unroll
  for (int j = 0; j < 8; ++j) {
    float bias = mrow[j] ? 0.0f : -14427.0f;
    o[j] = (short)f2bf(f[j] * L2E + bias);
  }
  ((s16x8*)dst)[i] = o;
}

// ---------------- QKV projection GEMM: C = X(bf16) * W^T + bias -------------
__global__ __launch_bounds__(256) void qkv_gemm(const unsigned short* __restrict__ X,
                                                const unsigned short* __restrict__ W3,
                                                const float* __restrict__ bq,
                                                const float* __restrict__ bk,
                                                const float* __restrict__ bv,
                                                unsigned short* __restrict__ O3) {
  const int mat = blockIdx.z;
  const unsigned short* Wp = W3 + (size_t)mat * (D_ * D_);
  const float* bias = (mat == 0) ? bq : (mat == 1) ? bk : bv;
  unsigned short* Op = O3 + (size_t)mat * ((size_t)B_ * S_ * D_);

  const int bm = blockIdx.y * 128, bn = blockIdx.x * 128;
  const int tid = threadIdx.x;
  const int lane = tid & 63, w = tid >> 6;
  const int wr = (w >> 1) * 64, wc = (w & 1) * 64;
  const int l15 = lane & 15, lh = lane >> 4;

  __shared__ __align__(16) unsigned short Al[128][72];
  __shared__ __align__(16) unsigned short Wl[128][72];

  f32x4 acc[4][4];
#pragma unroll
  for (int m = 0; m < 4; ++m)
#pragma unroll
    for (int n = 0; n < 4; ++n) acc[m][n] = (f32x4){0.f, 0.f, 0.f, 0.f};

  const int sr = tid >> 3, ss = tid & 7;

  for (int k0 = 0; k0 < D_; k0 += 64) {
    __syncthreads();
#pragma unroll
    for (int i = 0; i < 4; ++i) {
      int r = i * 32 + sr;
      *(s16x8*)(&Al[r][ss * 8]) =
          *(const s16x8*)(X + (size_t)(bm + r) * D_ + k0 + ss * 8);
      *(s16x8*)(&Wl[r][ss * 8]) =
          *(const s16x8*)(Wp + (size_t)(bn + r) * D_ + k0 + ss * 8);
    }
    __syncthreads();
#pragma unroll
    for (int kb = 0; kb < 2; ++kb) {
      s16x8 af[4], wf[4];
#pragma unroll
      for (int m = 0; m < 4; ++m)
        af[m] = *(const s16x8*)(&Al[wr + m * 16 + l15][kb * 32 + lh * 8]);
#pragma unroll
      for (int n = 0; n < 4; ++n)
        wf[n] = *(const s16x8*)(&Wl[wc + n * 16 + l15][kb * 32 + lh * 8]);
#pragma unroll
      for (int m = 0; m < 4; ++m)
#pragma unroll
        for (int n = 0; n < 4; ++n)
          acc[m][n] =
              __builtin_amdgcn_mfma_f32_16x16x32_bf16(af[m], wf[n], acc[m][n], 0, 0, 0);
    }
  }

#pragma unroll
  for (int n = 0; n < 4; ++n) {
    int col = bn + wc + n * 16 + l15;
    float bval = bias[col];
#pragma unroll
    for (int m = 0; m < 4; ++m) {
      int row0 = bm + wr + m * 16 + lh * 4;
#pragma unroll
      for (int r = 0; r < 4; ++r)
        Op[(size_t)(row0 + r) * D_ + col] = f2bf(acc[m][n][r] + bval);
    }
  }
}

// ---------------- V transpose: [B*S][D] -> [B][H][64][S] --------------------
__global__ __launch_bounds__(256) void vt_kernel(const unsigned short* __restrict__ Vin,
                                                 unsigned short* __restrict__ VT) {
  __shared__ unsigned short t[64][65];
  const int st = blockIdx.x, h = blockIdx.y, b = blockIdx.z;
  const int tid = threadIdx.x;
  const int r = tid >> 3, s = tid & 7;
#pragma unroll
  for (int i = 0; i < 2; ++i) {
    int key = i * 32 + r;
    s16x8 v = *(const s16x8*)(Vin + (size_t)(b * S_ + st * 64 + key) * D_ + h * HW_ + s * 8);
#pragma unroll
    for (int j = 0; j < 8; ++j) t[key][s * 8 + j] = (unsigned short)v[j];
  }
  __syncthreads();
#pragma unroll
  for (int i = 0; i < 2; ++i) {
    int d = i * 32 + r;
    s16x8 v;
#pragma unroll
    for (int j = 0; j < 8; ++j) v[j] = (short)t[s * 8 + j][d];
    *(s16x8*)(VT + ((size_t)(b * H_ + h) * HW_ + d) * S_ + st * 64 + s * 8) = v;
  }
}

// ---------------- fused flash attention (swapped-operand) -------------------
// grid (H, S/64, B), 256 threads = 4 waves; wave owns 16 q-rows (q = q0+l15).
// S^T = mfma(K_frag, Q_frag): per lane, all 16 scores belong to q = l15.
// O^T = mfma(VT_frag, PT_frag): accumulator col = q = l15 -> lane-uniform m/l.
__global__ __launch_bounds__(256, 4) void attn_kernel(
    const unsigned short* __restrict__ Q,
    const unsigned short* __restrict__ K,
    const unsigned short* __restrict__ VT,
    const unsigned short* __restrict__ POSM,  // bf16: pos*log2e + maskbias*log2e
    float* __restrict__ OUT) {
  const int h = blockIdx.x, qt = blockIdx.y, b = blockIdx.z;
  const int tid = threadIdx.x;
  const int lane = tid & 63, w = tid >> 6;
  const int l15 = lane & 15, lh = lane >> 4;

  __shared__ __align__(16) unsigned short Kl[64][72];    // [key][d]
  __shared__ __align__(16) unsigned short Vl[64][72];    // [d][key] (from VT)
  __shared__ __align__(16) unsigned short Pl[4][16][72]; // per-wave [q][key]

  const int q0 = qt * 64 + w * 16;
  const int qg = q0 + l15;  // this lane's q row
  s16x8 qf[2];
  {
    const unsigned short* qp = Q + (size_t)(b * S_ + qg) * D_ + h * HW_ + lh * 8;
    qf[0] = *(const s16x8*)qp;
    qf[1] = *(const s16x8*)(qp + 32);
  }

  f32x4 Oc[4];
#pragma unroll
  for (int n = 0; n < 4; ++n) Oc[n] = (f32x4){0.f, 0.f, 0.f, 0.f};
  float mrow = -1e30f, lrow = 0.f;

  const unsigned short* Kbase = K + (size_t)b * S_ * D_ + h * HW_;
  const unsigned short* Vbase = VT + ((size_t)(b * H_ + h) * HW_) * S_;
  const unsigned short* Pbase = POSM + (size_t)(b * S_ + qg) * S_;  // lane's pos row

  const float CSC = 0.125f * 1.4426950408889634f;  // scale * log2e

  for (int kt = 0; kt < S_ / 64; ++kt) {
    const int k0 = kt * 64;
    __syncthreads();
#pragma unroll
    for (int i = 0; i < 2; ++i) {
      int idx = i * 256 + tid;
      int r = idx >> 3, s = idx & 7;
      *(s16x8*)(&Kl[r][s * 8]) =
          *(const s16x8*)(Kbase + (size_t)(k0 + r) * D_ + s * 8);
      *(s16x8*)(&Vl[r][s * 8]) =
          *(const s16x8*)(Vbase + (size_t)r * S_ + k0 + s * 8);
    }
    // pos+mask for this lane's q row: 4x 8B vector loads (overlap with staging)
    u16x4 pm[4];
#pragma unroll
    for (int n = 0; n < 4; ++n)
      pm[n] = *(const u16x4*)(Pbase + k0 + n * 16 + lh * 4);
    __syncthreads();

    // QK^T (swapped): sc[n] reg r -> key = k0 + n*16 + lh*4 + r, q = l15
    f32x4 sc[4];
#pragma unroll
    for (int n = 0; n < 4; ++n) {
      s16x8 kf0 = *(const s16x8*)(&Kl[n * 16 + l15][lh * 8]);
      s16x8 kf1 = *(const s16x8*)(&Kl[n * 16 + l15][32 + lh * 8]);
      f32x4 s0 = (f32x4){0.f, 0.f, 0.f, 0.f};
      s0 = __builtin_amdgcn_mfma_f32_16x16x32_bf16(kf0, qf[0], s0, 0, 0, 0);
      s0 = __builtin_amdgcn_mfma_f32_16x16x32_bf16(kf1, qf[1], s0, 0, 0, 0);
      sc[n] = s0;
    }

    // fix: log2-domain score = qk*(0.125*log2e) + posm
#pragma unroll
    for (int n = 0; n < 4; ++n)
#pragma unroll
      for (int r = 0; r < 4; ++r)
        sc[n][r] = sc[n][r] * CSC + bf2f((unsigned short)pm[n][r]);

    // online softmax (all state per q = lane-uniform)
    float v01 = fmaxf(fmaxf(sc[0][0], sc[0][1]), fmaxf(sc[0][2], sc[0][3]));
    float v11 = fmaxf(fmaxf(sc[1][0], sc[1][1]), fmaxf(sc[1][2], sc[1][3]));
    float v21 = fmaxf(fmaxf(sc[2][0], sc[2][1]), fmaxf(sc[2][2], sc[2][3]));
    float v31 = fmaxf(fmaxf(sc[3][0], sc[3][1]), fmaxf(sc[3][2], sc[3][3]));
    float v = fmaxf(fmaxf(v01, v11), fmaxf(v21, v31));
    v = fmaxf(v, __shfl_xor(v, 16, 64));
    v = fmaxf(v, __shfl_xor(v, 32, 64));
    float mnew = fmaxf(mrow, v);
    float alpha = exp2f(mrow - mnew);
    mrow = mnew;

    float rsum = 0.f;
#pragma unroll
    for (int n = 0; n < 4; ++n)
#pragma unroll
      for (int r = 0; r < 4; ++r) {
        float p = exp2f(sc[n][r] - mrow);
        sc[n][r] = p;
        rsum += p;
      }
    rsum += __shfl_xor(rsum, 16, 64);
    rsum += __shfl_xor(rsum, 32, 64);
    lrow = lrow * alpha + rsum;

#pragma unroll
    for (int n = 0; n < 4; ++n)
#pragma unroll
      for (int r = 0; r < 4; ++r) Oc[n][r] *= alpha;

    // pack P -> per-wave LDS [q][key], 8B vectorized writes
#pragma unroll
    for (int n = 0; n < 4; ++n) {
      unsigned int w0 = (unsigned int)f2bf(sc[n][0]) |
                        ((unsigned int)f2bf(sc[n][1]) << 16);
      unsigned int w1 = (unsigned int)f2bf(sc[n][2]) |
                        ((unsigned int)f2bf(sc[n][3]) << 16);
      *(u32x2*)(&Pl[w][l15][n * 16 + lh * 4]) = (u32x2){w0, w1};
    }

    // PV (swapped): Oc[n] = mfma(VT_frag, PT_frag) -> O^T, col = q = l15
#pragma unroll
    for (int kb = 0; kb < 2; ++kb) {
      s16x8 pf = *(const s16x8*)(&Pl[w][l15][kb * 32 + lh * 8]);
#pragma unroll
      for (int n = 0; n < 4; ++n) {
        s16x8 vf = *(const s16x8*)(&Vl[n * 16 + l15][kb * 32 + lh * 8]);
        Oc[n] = __builtin_amdgcn_mfma_f32_16x16x32_bf16(vf, pf, Oc[n], 0, 0, 0);
      }
    }
  }

  // epilogue: lane-uniform 1/l; O^T reg (n,r) -> OUT[qg][h*64 + n*16 + lh*4 + r]
  float inv = 1.0f / lrow;
#pragma unroll
  for (int n = 0; n < 4; ++n)
#pragma unroll
    for (int r = 0; r < 4; ++r)
      OUT[(size_t)(b * S_ + qg) * D_ + h * HW_ + n * 16 + lh * 4 + r] =
          Oc[n][r] * inv;
}

// ---------------- launcher ---------------------------------------------------
extern "C" void kernel_launch(void* const* d_in, const int* in_sizes, int n_in,
                              void* d_out, int out_size, void* d_ws, size_t ws_size,
                              hipStream_t stream) {
  const float* x   = (const float*)d_in[0];
  const int*   msk = (const int*)d_in[1];
  const float* pos = (const float*)d_in[2];
  const float* wq  = (const float*)d_in[3];
  const float* bq  = (const float*)d_in[4];
  const float* wk  = (const float*)d_in[5];
  const float* bk  = (const float*)d_in[6];
  const float* wv  = (const float*)d_in[7];
  const float* bv  = (const float*)d_in[8];
  float* out = (float*)d_out;

  char* ws = (char*)d_ws;
  // layout: xb(8MB) | wb(6MB) | qkv(24MB) | posb(16MB) | vt(8MB)
  unsigned short* xb   = (unsigned short*)(ws);
  unsigned short* wb   = (unsigned short*)(ws + 8388608);
  unsigned short* qkv  = (unsigned short*)(ws + 14680064);
  unsigned short* posb = (unsigned short*)(ws + 39845888);
  unsigned short* vt   = (unsigned short*)(ws + 56623104);

  cvt_f32_bf16<<<2048, 256, 0, stream>>>(x, xb, (B_ * S_ * D_) / 8);
  cvt_f32_bf16<<<512, 256, 0, stream>>>(wq, wb, (D_ * D_) / 8);
  cvt_f32_bf16<<<512, 256, 0, stream>>>(wk, wb + D_ * D_, (D_ * D_) / 8);
  cvt_f32_bf16<<<512, 256, 0, stream>>>(wv, wb + 2 * D_ * D_, (D_ * D_) / 8);
  cvt_pos<<<4096, 256, 0, stream>>>(pos, msk, posb);

  qkv_gemm<<<dim3(D_ / 128, (B_ * S_) / 128, 3), 256, 0, stream>>>(
      xb, wb, bq, bk, bv, qkv);

  vt_kernel<<<dim3(S_ / 64, H_, B_), 256, 0, stream>>>(
      qkv + 2 * (size_t)B_ * S_ * D_, vt);

  attn_kernel<<<dim3(H_, S_ / 64, B_), 256, 0, stream>>>(
      qkv, qkv + (size_t)B_ * S_ * D_, vt, posb, out);
}